// Round 7
// baseline (198.740 us; speedup 1.0000x reference)
//
#include <hip/hip_runtime.h>

#define NIMG 64
#define H 512
#define W 512

constexpr float THR_64  = 50.0f / 255.0f;          // level_idx=1: 64x64 details
constexpr float THR_128 = 50.0f / 2.0f / 255.0f;   // level_idx=2: 128x128
constexpr float THR_256 = 50.0f / 4.0f / 255.0f;   // level_idx=3: 256x256

__device__ __forceinline__ float wave_sum(float v) {
#pragma unroll
    for (int o = 32; o > 0; o >>= 1) v += __shfl_down(v, o, 64);
    return v;
}

__device__ __forceinline__ float clip01(float x) {
    return fminf(fmaxf(x, 0.0f), 1.0f);
}

__device__ __forceinline__ float4 clip4(float4 p) {
    p.x = clip01(p.x); p.y = clip01(p.y); p.z = clip01(p.z); p.w = clip01(p.w);
    return p;
}

// Kernel A: sequential-streaming LDS-staged fused kernel.
// Block = 8-row full-width slab (16 KB/stream). Phase 1: threads load the
// slab of pred/noisy/mask as CONSECUTIVE float4s (dense 32KB-segment
// coverage per stream -> even L2-channel utilization), fuse n2v, stage
// clipped pred in LDS (+1 halo row). Phase 2: wave wv = (row-quad q2, col
// half h); lane owns a 4x4 patch = one level-2 quad, all reads from LDS.
// LDS = 9*512*4 = 18 KB -> 8 blocks/CU = 32 waves/CU. No atomics.
// Grid = 64 imgs * 64 slabs = 4096 blocks.
__global__ __launch_bounds__(256) void kA(const float* __restrict__ pred,
                                          const float* __restrict__ noisy,
                                          const int* __restrict__ mask,
                                          float4* __restrict__ pA,
                                          float* __restrict__ pW2,
                                          float* __restrict__ ll2) {
    __shared__ float sl[9 * 512];
    __shared__ float red[4][5];

    const int tid = threadIdx.x;
    const int lane = tid & 63;
    const int wv = tid >> 6;
    const int bid = blockIdx.x;
    const int n = bid >> 6;                  // image
    const int s = bid & 63;                  // slab (8 rows)
    const int r0 = s << 3;                   // first global row
    const size_t base = (size_t)n * (H * W) + (size_t)r0 * W;

    // ---------- phase 1: dense sequential streaming + n2v + stage ----------
    float n2v = 0.0f, msum = 0.0f;
#pragma unroll
    for (int k = 0; k < 4; ++k) {
        const int idx = tid + (k << 8);      // 0..1023 consecutive float4 slots
        const size_t off = base + (size_t)idx * 4;
        float4 p = *reinterpret_cast<const float4*>(pred + off);
        float4 nz = *reinterpret_cast<const float4*>(noisy + off);
        int4 mk = *reinterpret_cast<const int4*>(mask + off);
        p = clip4(p);
        float m;
        m = mk.x ? 1.f : 0.f; n2v += fabsf(p.x - nz.x) * m; msum += m;
        m = mk.y ? 1.f : 0.f; n2v += fabsf(p.y - nz.y) * m; msum += m;
        m = mk.z ? 1.f : 0.f; n2v += fabsf(p.z - nz.z) * m; msum += m;
        m = mk.w ? 1.f : 0.f; n2v += fabsf(p.w - nz.w) * m; msum += m;
        *reinterpret_cast<float4*>(&sl[idx << 2]) = p;
    }
    // halo row (global row r0-1) -> LDS row 8 (zeros if r0 == 0)
    if (tid < 128) {
        float4 hp = make_float4(0.f, 0.f, 0.f, 0.f);
        if (r0 > 0) {
            hp = clip4(*reinterpret_cast<const float4*>(pred + base - W + (size_t)tid * 4));
        }
        *reinterpret_cast<float4*>(&sl[(8 << 9) + (tid << 2)]) = hp;
    }
    __syncthreads();

    // ---------- phase 2: TV + level-1 + level-2 Haar from LDS ----------
    const int q2 = wv >> 1;                  // row quad within slab: 0 or 1
    const int h = wv & 1;                    // col half
    const int cofs = (h << 8) + (lane << 2);
    const float* rowp = sl + (q2 << 11);     // 4*q2 rows * 512

    float4 p0 = *reinterpret_cast<const float4*>(rowp + cofs);
    float4 p1 = *reinterpret_cast<const float4*>(rowp + 512 + cofs);
    float4 p2 = *reinterpret_cast<const float4*>(rowp + 1024 + cofs);
    float4 p3 = *reinterpret_cast<const float4*>(rowp + 1536 + cofs);
    // halo for this quad: q2==1 -> slab row 3; q2==0 -> staged halo row 8
    const float* hrow = (q2 == 1) ? (sl + 3 * 512) : (sl + 8 * 512);
    float4 hl = *reinterpret_cast<const float4*>(hrow + cofs);
    const bool has_halo = (q2 == 1) || (r0 > 0);

    float tv = 0.0f;
    // horizontal interior
    tv += fabsf(p0.y - p0.x) + fabsf(p0.z - p0.y) + fabsf(p0.w - p0.z);
    tv += fabsf(p1.y - p1.x) + fabsf(p1.z - p1.y) + fabsf(p1.w - p1.z);
    tv += fabsf(p2.y - p2.x) + fabsf(p2.z - p2.y) + fabsf(p2.w - p2.z);
    tv += fabsf(p3.y - p3.x) + fabsf(p3.z - p3.y) + fabsf(p3.w - p3.z);
    // horizontal boundary to next lane (shfl), seam col 255|256 from LDS
    float nx0 = __shfl_down(p0.x, 1, 64);
    float nx1 = __shfl_down(p1.x, 1, 64);
    float nx2 = __shfl_down(p2.x, 1, 64);
    float nx3 = __shfl_down(p3.x, 1, 64);
    if (lane < 63) {
        tv += fabsf(nx0 - p0.w) + fabsf(nx1 - p1.w)
            + fabsf(nx2 - p2.w) + fabsf(nx3 - p3.w);
    } else if (h == 0) {
        tv += fabsf(rowp[256] - p0.w) + fabsf(rowp[512 + 256] - p1.w)
            + fabsf(rowp[1024 + 256] - p2.w) + fabsf(rowp[1536 + 256] - p3.w);
    }
    // vertical internal + halo
    tv += fabsf(p1.x - p0.x) + fabsf(p1.y - p0.y) + fabsf(p1.z - p0.z) + fabsf(p1.w - p0.w);
    tv += fabsf(p2.x - p1.x) + fabsf(p2.y - p1.y) + fabsf(p2.z - p1.z) + fabsf(p2.w - p1.w);
    tv += fabsf(p3.x - p2.x) + fabsf(p3.y - p2.y) + fabsf(p3.z - p2.z) + fabsf(p3.w - p2.w);
    if (has_halo) {
        tv += fabsf(p0.x - hl.x) + fabsf(p0.y - hl.y)
            + fabsf(p0.z - hl.z) + fabsf(p0.w - hl.w);
    }

    // level-1 Haar: 4 quads per lane
    float wav1 = 0.0f;
    float a, b, c, d, ch, cv, cd;
    a = p0.x; b = p0.y; c = p1.x; d = p1.y;
    float llA0 = (a + b + c + d) * 0.5f;
    ch = (a + b - c - d) * 0.5f; cv = (a - b + c - d) * 0.5f; cd = (a - b - c + d) * 0.5f;
    wav1 += fminf(fabsf(ch), THR_256) + fminf(fabsf(cv), THR_256) + fminf(fabsf(cd), THR_256);
    a = p0.z; b = p0.w; c = p1.z; d = p1.w;
    float llA1 = (a + b + c + d) * 0.5f;
    ch = (a + b - c - d) * 0.5f; cv = (a - b + c - d) * 0.5f; cd = (a - b - c + d) * 0.5f;
    wav1 += fminf(fabsf(ch), THR_256) + fminf(fabsf(cv), THR_256) + fminf(fabsf(cd), THR_256);
    a = p2.x; b = p2.y; c = p3.x; d = p3.y;
    float llB0 = (a + b + c + d) * 0.5f;
    ch = (a + b - c - d) * 0.5f; cv = (a - b + c - d) * 0.5f; cd = (a - b - c + d) * 0.5f;
    wav1 += fminf(fabsf(ch), THR_256) + fminf(fabsf(cv), THR_256) + fminf(fabsf(cd), THR_256);
    a = p2.z; b = p2.w; c = p3.z; d = p3.w;
    float llB1 = (a + b + c + d) * 0.5f;
    ch = (a + b - c - d) * 0.5f; cv = (a - b + c - d) * 0.5f; cd = (a - b - c + d) * 0.5f;
    wav1 += fminf(fabsf(ch), THR_256) + fminf(fabsf(cv), THR_256) + fminf(fabsf(cd), THR_256);

    // level-2 Haar: lane-local quad
    float wav2;
    float ll2v;
    {
        a = llA0; b = llA1; c = llB0; d = llB1;
        ll2v = (a + b + c + d) * 0.5f;
        ch = (a + b - c - d) * 0.5f;
        cv = (a - b + c - d) * 0.5f;
        cd = (a - b - c + d) * 0.5f;
        wav2 = fminf(fabsf(ch), THR_128) + fminf(fabsf(cv), THR_128) + fminf(fabsf(cd), THR_128);
    }
    // LL2 row = 2s + q2, col = 64h + lane (wave writes 256 B contiguous)
    ll2[(size_t)n * 16384 + (size_t)((s << 1) + q2) * 128 + (h << 6) + lane] = ll2v;

    // ---------- block reduction -> plain stores ----------
    float v0 = wave_sum(n2v);
    float v1 = wave_sum(msum);
    float v2 = wave_sum(tv);
    float v3 = wave_sum(wav1);
    float v4 = wave_sum(wav2);
    if (lane == 0) {
        red[wv][0] = v0; red[wv][1] = v1; red[wv][2] = v2;
        red[wv][3] = v3; red[wv][4] = v4;
    }
    __syncthreads();
    if (tid == 0) {
        pA[bid] = make_float4(red[0][0] + red[1][0] + red[2][0] + red[3][0],
                              red[0][1] + red[1][1] + red[2][1] + red[3][1],
                              red[0][2] + red[1][2] + red[2][2] + red[3][2],
                              red[0][3] + red[1][3] + red[2][3] + red[3][3]);
        pW2[bid] = red[0][4] + red[1][4] + red[2][4] + red[3][4];
    }
}

// Kernel C: level-3 details from LL2 (64x128x128, 4 MB). Grid = 128 blocks,
// 8 quads/thread. Partials to pC[bid].
__global__ __launch_bounds__(256) void kC(const float* __restrict__ ll2,
                                          float* __restrict__ pC) {
    __shared__ float red[4];
    const int tid = threadIdx.x;
    const int lane = tid & 63, wv = tid >> 6;
    const int bid = blockIdx.x;
    const int n = bid >> 1;
    const int s = bid & 1;                      // quad-row half [32s, 32s+32)
    const float* src = ll2 + (size_t)n * 16384;

    float wav3 = 0.0f;
#pragma unroll
    for (int i = 0; i < 8; ++i) {
        int u = (i << 8) + tid;                 // 0..2047
        int qr = (s << 5) + (u >> 6);           // 0..63
        int qc = u & 63;
        float2 top = *reinterpret_cast<const float2*>(src + (2 * qr) * 128 + 2 * qc);
        float2 bot = *reinterpret_cast<const float2*>(src + (2 * qr + 1) * 128 + 2 * qc);
        float a = top.x, b = top.y, c = bot.x, d = bot.y;
        float ch = (a + b - c - d) * 0.5f;
        float cv = (a - b + c - d) * 0.5f;
        float cd = (a - b - c + d) * 0.5f;
        wav3 += fminf(fabsf(ch), THR_64) + fminf(fabsf(cv), THR_64) + fminf(fabsf(cd), THR_64);
    }
    float v = wave_sum(wav3);
    if (lane == 0) red[wv] = v;
    __syncthreads();
    if (tid == 0) pC[bid] = red[0] + red[1] + red[2] + red[3];
}

// Kernel D: reduce partials (4096 float4 + 4096 float + 128 float), compose.
__global__ __launch_bounds__(256) void kD(const float4* __restrict__ pA,
                                          const float* __restrict__ pW2,
                                          const float* __restrict__ pC,
                                          float* __restrict__ out) {
    __shared__ float red[4][6];
    const int tid = threadIdx.x;
    const int lane = tid & 63, wv = tid >> 6;

    float s0 = 0, s1 = 0, s2 = 0, s3 = 0, s4 = 0, s5 = 0;
#pragma unroll
    for (int j = 0; j < 16; ++j) {
        float4 v = pA[tid + (j << 8)];
        s0 += v.x; s1 += v.y; s2 += v.z; s3 += v.w;
        s4 += pW2[tid + (j << 8)];
    }
    if (tid < 128) s5 = pC[tid];

    s0 = wave_sum(s0); s1 = wave_sum(s1); s2 = wave_sum(s2);
    s3 = wave_sum(s3); s4 = wave_sum(s4); s5 = wave_sum(s5);
    if (lane == 0) {
        red[wv][0] = s0; red[wv][1] = s1; red[wv][2] = s2;
        red[wv][3] = s3; red[wv][4] = s4; red[wv][5] = s5;
    }
    __syncthreads();
    if (tid == 0) {
        float a0 = red[0][0] + red[1][0] + red[2][0] + red[3][0];
        float a1 = red[0][1] + red[1][1] + red[2][1] + red[3][1];
        float a2 = red[0][2] + red[1][2] + red[2][2] + red[3][2];
        float a3 = red[0][3] + red[1][3] + red[2][3] + red[3][3];
        float a4 = red[0][4] + red[1][4] + red[2][4] + red[3][4];
        float a5 = red[0][5] + red[1][5] + red[2][5] + red[3][5];
        float n2v = a0 / fmaxf(a1, 1.0f);
        float tv = a2 / 16744448.0f;                   // 64*511*512 (both terms)
        float wav = a3 * (1.0f / 37748736.0f)          // (1/3) / (3*64*256*256)
                  + a4 * (1.0f / 6291456.0f)           // (1/2) / (3*64*128*128)
                  + a5 * (1.0f / 786432.0f);           // 1     / (3*64*64*64)
        out[0] = 1.0f * n2v + 0.2f * wav + 0.01f * tv;
    }
}

extern "C" void kernel_launch(void* const* d_in, const int* in_sizes, int n_in,
                              void* d_out, int out_size, void* d_ws, size_t ws_size,
                              hipStream_t stream) {
    (void)in_sizes; (void)n_in; (void)out_size; (void)ws_size;
    const float* pred  = (const float*)d_in[0];
    const float* noisy = (const float*)d_in[1];
    const int*   mask  = (const int*)d_in[2];

    float4* pA  = (float4*)d_ws;                          // 4096 * 16 B = 64 KB
    float*  pW2 = (float*)((char*)d_ws + 65536);          // 4096 * 4 B = 16 KB
    float*  pC  = (float*)((char*)d_ws + 81920);          // 128 * 4 B
    float*  ll2 = (float*)((char*)d_ws + 98304);          // 64*128*128 floats = 4 MB

    kA<<<4096, 256, 0, stream>>>(pred, noisy, mask, pA, pW2, ll2);
    kC<<<128, 256, 0, stream>>>(ll2, pC);
    kD<<<1, 256, 0, stream>>>(pA, pW2, pC, (float*)d_out);
}

// Round 8
// 190.115 us; speedup vs baseline: 1.0454x; 1.0454x over previous
//
#include <hip/hip_runtime.h>

#define NIMG 64
#define H 512
#define W 512

constexpr float THR_64  = 50.0f / 255.0f;          // level_idx=1: 64x64 details
constexpr float THR_128 = 50.0f / 2.0f / 255.0f;   // level_idx=2: 128x128
constexpr float THR_256 = 50.0f / 4.0f / 255.0f;   // level_idx=3: 256x256

__device__ __forceinline__ float wave_sum(float v) {
#pragma unroll
    for (int o = 32; o > 0; o >>= 1) v += __shfl_down(v, o, 64);
    return v;
}

__device__ __forceinline__ float clip01(float x) {
    return fminf(fmaxf(x, 0.0f), 1.0f);
}

__device__ __forceinline__ float4 clip4(float4 p) {
    p.x = clip01(p.x); p.y = clip01(p.y); p.z = clip01(p.z); p.w = clip01(p.w);
    return p;
}

// Kernel A: R7 structure + SPARSE noisy loads. Phase 1 loads pred+mask for
// the whole 8-row slab up front (8 independent dwordx4/wave), then loads each
// noisy float4 only if any of its 4 mask bits is set (exec-masked: ~7.8% of
// lanes -> ~28% of noisy lines fetched). Read volume 192 -> ~146 MB.
// LDS = 18 KB -> 8 blocks/CU. No atomics. Grid = 64*64 = 4096 blocks.
__global__ __launch_bounds__(256) void kA(const float* __restrict__ pred,
                                          const float* __restrict__ noisy,
                                          const int* __restrict__ mask,
                                          float4* __restrict__ pA,
                                          float* __restrict__ pW2,
                                          float* __restrict__ ll2) {
    __shared__ float sl[9 * 512];
    __shared__ float red[4][5];

    const int tid = threadIdx.x;
    const int lane = tid & 63;
    const int wv = tid >> 6;
    const int bid = blockIdx.x;
    const int n = bid >> 6;                  // image
    const int s = bid & 63;                  // slab (8 rows)
    const int r0 = s << 3;                   // first global row
    const size_t base = (size_t)n * (H * W) + (size_t)r0 * W;
    const size_t o0 = base + (size_t)tid * 4;   // this thread's chunk-0 offset

    // ---------- phase 1a: pred + mask for all 4 chunks, issued up front ----------
    float4 p0 = *reinterpret_cast<const float4*>(pred + o0);
    float4 p1 = *reinterpret_cast<const float4*>(pred + o0 + 1024);
    float4 p2 = *reinterpret_cast<const float4*>(pred + o0 + 2048);
    float4 p3 = *reinterpret_cast<const float4*>(pred + o0 + 3072);
    int4 m0 = *reinterpret_cast<const int4*>(mask + o0);
    int4 m1 = *reinterpret_cast<const int4*>(mask + o0 + 1024);
    int4 m2 = *reinterpret_cast<const int4*>(mask + o0 + 2048);
    int4 m3 = *reinterpret_cast<const int4*>(mask + o0 + 3072);
    // halo row (global row r0-1) -> LDS row 8 (zeros if r0 == 0)
    if (tid < 128) {
        float4 hp = make_float4(0.f, 0.f, 0.f, 0.f);
        if (r0 > 0) {
            hp = clip4(*reinterpret_cast<const float4*>(pred + base - W + (size_t)tid * 4));
        }
        *reinterpret_cast<float4*>(&sl[(8 << 9) + (tid << 2)]) = hp;
    }

    // ---------- phase 1b: sparse noisy + n2v + stage clipped pred ----------
    float n2v = 0.0f, msum = 0.0f;
#define CHUNK(P, MK, OFS)                                                        \
    {                                                                            \
        float4 nz = make_float4(0.f, 0.f, 0.f, 0.f);                             \
        if ((MK.x | MK.y | MK.z | MK.w) != 0)                                    \
            nz = *reinterpret_cast<const float4*>(noisy + (OFS));                \
        P = clip4(P);                                                            \
        float m;                                                                 \
        m = MK.x ? 1.f : 0.f; n2v += fabsf(P.x - nz.x) * m; msum += m;           \
        m = MK.y ? 1.f : 0.f; n2v += fabsf(P.y - nz.y) * m; msum += m;           \
        m = MK.z ? 1.f : 0.f; n2v += fabsf(P.z - nz.z) * m; msum += m;           \
        m = MK.w ? 1.f : 0.f; n2v += fabsf(P.w - nz.w) * m; msum += m;           \
    }
    CHUNK(p0, m0, o0)
    CHUNK(p1, m1, o0 + 1024)
    CHUNK(p2, m2, o0 + 2048)
    CHUNK(p3, m3, o0 + 3072)
#undef CHUNK
    *reinterpret_cast<float4*>(&sl[tid << 2]) = p0;
    *reinterpret_cast<float4*>(&sl[(tid + 256) << 2]) = p1;
    *reinterpret_cast<float4*>(&sl[(tid + 512) << 2]) = p2;
    *reinterpret_cast<float4*>(&sl[(tid + 768) << 2]) = p3;
    __syncthreads();

    // ---------- phase 2: TV + level-1 + level-2 Haar from LDS ----------
    const int q2 = wv >> 1;                  // row quad within slab: 0 or 1
    const int h = wv & 1;                    // col half
    const int cofs = (h << 8) + (lane << 2);
    const float* rowp = sl + (q2 << 11);     // 4*q2 rows * 512

    float4 q0 = *reinterpret_cast<const float4*>(rowp + cofs);
    float4 q1 = *reinterpret_cast<const float4*>(rowp + 512 + cofs);
    float4 qq2 = *reinterpret_cast<const float4*>(rowp + 1024 + cofs);
    float4 q3 = *reinterpret_cast<const float4*>(rowp + 1536 + cofs);
    // halo for this quad: q2==1 -> slab row 3; q2==0 -> staged halo row 8
    const float* hrow = (q2 == 1) ? (sl + 3 * 512) : (sl + 8 * 512);
    float4 hl = *reinterpret_cast<const float4*>(hrow + cofs);
    const bool has_halo = (q2 == 1) || (r0 > 0);

    float tv = 0.0f;
    // horizontal interior
    tv += fabsf(q0.y - q0.x) + fabsf(q0.z - q0.y) + fabsf(q0.w - q0.z);
    tv += fabsf(q1.y - q1.x) + fabsf(q1.z - q1.y) + fabsf(q1.w - q1.z);
    tv += fabsf(qq2.y - qq2.x) + fabsf(qq2.z - qq2.y) + fabsf(qq2.w - qq2.z);
    tv += fabsf(q3.y - q3.x) + fabsf(q3.z - q3.y) + fabsf(q3.w - q3.z);
    // horizontal boundary to next lane (shfl), seam col 255|256 from LDS
    float nx0 = __shfl_down(q0.x, 1, 64);
    float nx1 = __shfl_down(q1.x, 1, 64);
    float nx2 = __shfl_down(qq2.x, 1, 64);
    float nx3 = __shfl_down(q3.x, 1, 64);
    if (lane < 63) {
        tv += fabsf(nx0 - q0.w) + fabsf(nx1 - q1.w)
            + fabsf(nx2 - qq2.w) + fabsf(nx3 - q3.w);
    } else if (h == 0) {
        tv += fabsf(rowp[256] - q0.w) + fabsf(rowp[512 + 256] - q1.w)
            + fabsf(rowp[1024 + 256] - qq2.w) + fabsf(rowp[1536 + 256] - q3.w);
    }
    // vertical internal + halo
    tv += fabsf(q1.x - q0.x) + fabsf(q1.y - q0.y) + fabsf(q1.z - q0.z) + fabsf(q1.w - q0.w);
    tv += fabsf(qq2.x - q1.x) + fabsf(qq2.y - q1.y) + fabsf(qq2.z - q1.z) + fabsf(qq2.w - q1.w);
    tv += fabsf(q3.x - qq2.x) + fabsf(q3.y - qq2.y) + fabsf(q3.z - qq2.z) + fabsf(q3.w - qq2.w);
    if (has_halo) {
        tv += fabsf(q0.x - hl.x) + fabsf(q0.y - hl.y)
            + fabsf(q0.z - hl.z) + fabsf(q0.w - hl.w);
    }

    // level-1 Haar: 4 quads per lane
    float wav1 = 0.0f;
    float a, b, c, d, ch, cv, cd;
    a = q0.x; b = q0.y; c = q1.x; d = q1.y;
    float llA0 = (a + b + c + d) * 0.5f;
    ch = (a + b - c - d) * 0.5f; cv = (a - b + c - d) * 0.5f; cd = (a - b - c + d) * 0.5f;
    wav1 += fminf(fabsf(ch), THR_256) + fminf(fabsf(cv), THR_256) + fminf(fabsf(cd), THR_256);
    a = q0.z; b = q0.w; c = q1.z; d = q1.w;
    float llA1 = (a + b + c + d) * 0.5f;
    ch = (a + b - c - d) * 0.5f; cv = (a - b + c - d) * 0.5f; cd = (a - b - c + d) * 0.5f;
    wav1 += fminf(fabsf(ch), THR_256) + fminf(fabsf(cv), THR_256) + fminf(fabsf(cd), THR_256);
    a = qq2.x; b = qq2.y; c = q3.x; d = q3.y;
    float llB0 = (a + b + c + d) * 0.5f;
    ch = (a + b - c - d) * 0.5f; cv = (a - b + c - d) * 0.5f; cd = (a - b - c + d) * 0.5f;
    wav1 += fminf(fabsf(ch), THR_256) + fminf(fabsf(cv), THR_256) + fminf(fabsf(cd), THR_256);
    a = qq2.z; b = qq2.w; c = q3.z; d = q3.w;
    float llB1 = (a + b + c + d) * 0.5f;
    ch = (a + b - c - d) * 0.5f; cv = (a - b + c - d) * 0.5f; cd = (a - b - c + d) * 0.5f;
    wav1 += fminf(fabsf(ch), THR_256) + fminf(fabsf(cv), THR_256) + fminf(fabsf(cd), THR_256);

    // level-2 Haar: lane-local quad
    float wav2, ll2v;
    {
        a = llA0; b = llA1; c = llB0; d = llB1;
        ll2v = (a + b + c + d) * 0.5f;
        ch = (a + b - c - d) * 0.5f;
        cv = (a - b + c - d) * 0.5f;
        cd = (a - b - c + d) * 0.5f;
        wav2 = fminf(fabsf(ch), THR_128) + fminf(fabsf(cv), THR_128) + fminf(fabsf(cd), THR_128);
    }
    // LL2 row = 2s + q2, col = 64h + lane (wave writes 256 B contiguous)
    ll2[(size_t)n * 16384 + (size_t)((s << 1) + q2) * 128 + (h << 6) + lane] = ll2v;

    // ---------- block reduction -> plain stores ----------
    float v0 = wave_sum(n2v);
    float v1 = wave_sum(msum);
    float v2 = wave_sum(tv);
    float v3 = wave_sum(wav1);
    float v4 = wave_sum(wav2);
    if (lane == 0) {
        red[wv][0] = v0; red[wv][1] = v1; red[wv][2] = v2;
        red[wv][3] = v3; red[wv][4] = v4;
    }
    __syncthreads();
    if (tid == 0) {
        pA[bid] = make_float4(red[0][0] + red[1][0] + red[2][0] + red[3][0],
                              red[0][1] + red[1][1] + red[2][1] + red[3][1],
                              red[0][2] + red[1][2] + red[2][2] + red[3][2],
                              red[0][3] + red[1][3] + red[2][3] + red[3][3]);
        pW2[bid] = red[0][4] + red[1][4] + red[2][4] + red[3][4];
    }
}

// Kernel C: level-3 details from LL2 (64x128x128, 4 MB). Grid = 128 blocks,
// 8 quads/thread. Partials to pC[bid].
__global__ __launch_bounds__(256) void kC(const float* __restrict__ ll2,
                                          float* __restrict__ pC) {
    __shared__ float red[4];
    const int tid = threadIdx.x;
    const int lane = tid & 63, wv = tid >> 6;
    const int bid = blockIdx.x;
    const int n = bid >> 1;
    const int s = bid & 1;                      // quad-row half [32s, 32s+32)
    const float* src = ll2 + (size_t)n * 16384;

    float wav3 = 0.0f;
#pragma unroll
    for (int i = 0; i < 8; ++i) {
        int u = (i << 8) + tid;                 // 0..2047
        int qr = (s << 5) + (u >> 6);           // 0..63
        int qc = u & 63;
        float2 top = *reinterpret_cast<const float2*>(src + (2 * qr) * 128 + 2 * qc);
        float2 bot = *reinterpret_cast<const float2*>(src + (2 * qr + 1) * 128 + 2 * qc);
        float a = top.x, b = top.y, c = bot.x, d = bot.y;
        float ch = (a + b - c - d) * 0.5f;
        float cv = (a - b + c - d) * 0.5f;
        float cd = (a - b - c + d) * 0.5f;
        wav3 += fminf(fabsf(ch), THR_64) + fminf(fabsf(cv), THR_64) + fminf(fabsf(cd), THR_64);
    }
    float v = wave_sum(wav3);
    if (lane == 0) red[wv] = v;
    __syncthreads();
    if (tid == 0) pC[bid] = red[0] + red[1] + red[2] + red[3];
}

// Kernel D: reduce partials (4096 float4 + 4096 float + 128 float), compose.
__global__ __launch_bounds__(256) void kD(const float4* __restrict__ pA,
                                          const float* __restrict__ pW2,
                                          const float* __restrict__ pC,
                                          float* __restrict__ out) {
    __shared__ float red[4][6];
    const int tid = threadIdx.x;
    const int lane = tid & 63, wv = tid >> 6;

    float s0 = 0, s1 = 0, s2 = 0, s3 = 0, s4 = 0, s5 = 0;
#pragma unroll
    for (int j = 0; j < 16; ++j) {
        float4 v = pA[tid + (j << 8)];
        s0 += v.x; s1 += v.y; s2 += v.z; s3 += v.w;
        s4 += pW2[tid + (j << 8)];
    }
    if (tid < 128) s5 = pC[tid];

    s0 = wave_sum(s0); s1 = wave_sum(s1); s2 = wave_sum(s2);
    s3 = wave_sum(s3); s4 = wave_sum(s4); s5 = wave_sum(s5);
    if (lane == 0) {
        red[wv][0] = s0; red[wv][1] = s1; red[wv][2] = s2;
        red[wv][3] = s3; red[wv][4] = s4; red[wv][5] = s5;
    }
    __syncthreads();
    if (tid == 0) {
        float a0 = red[0][0] + red[1][0] + red[2][0] + red[3][0];
        float a1 = red[0][1] + red[1][1] + red[2][1] + red[3][1];
        float a2 = red[0][2] + red[1][2] + red[2][2] + red[3][2];
        float a3 = red[0][3] + red[1][3] + red[2][3] + red[3][3];
        float a4 = red[0][4] + red[1][4] + red[2][4] + red[3][4];
        float a5 = red[0][5] + red[1][5] + red[2][5] + red[3][5];
        float n2v = a0 / fmaxf(a1, 1.0f);
        float tv = a2 / 16744448.0f;                   // 64*511*512 (both terms)
        float wav = a3 * (1.0f / 37748736.0f)          // (1/3) / (3*64*256*256)
                  + a4 * (1.0f / 6291456.0f)           // (1/2) / (3*64*128*128)
                  + a5 * (1.0f / 786432.0f);           // 1     / (3*64*64*64)
        out[0] = 1.0f * n2v + 0.2f * wav + 0.01f * tv;
    }
}

extern "C" void kernel_launch(void* const* d_in, const int* in_sizes, int n_in,
                              void* d_out, int out_size, void* d_ws, size_t ws_size,
                              hipStream_t stream) {
    (void)in_sizes; (void)n_in; (void)out_size; (void)ws_size;
    const float* pred  = (const float*)d_in[0];
    const float* noisy = (const float*)d_in[1];
    const int*   mask  = (const int*)d_in[2];

    float4* pA  = (float4*)d_ws;                          // 4096 * 16 B = 64 KB
    float*  pW2 = (float*)((char*)d_ws + 65536);          // 4096 * 4 B = 16 KB
    float*  pC  = (float*)((char*)d_ws + 81920);          // 128 * 4 B
    float*  ll2 = (float*)((char*)d_ws + 98304);          // 64*128*128 floats = 4 MB

    kA<<<4096, 256, 0, stream>>>(pred, noisy, mask, pA, pW2, ll2);
    kC<<<128, 256, 0, stream>>>(ll2, pC);
    kD<<<1, 256, 0, stream>>>(pA, pW2, pC, (float*)d_out);
}